// Round 1
// baseline (263.524 us; speedup 1.0000x reference)
//
#include <hip/hip_runtime.h>

#define BATCH 8
#define NROW  2048
#define NF    64
#define TI    64
#define JT    64
#define NCHUNK (NROW / JT)   // 32

// out[b,i,f] = (sum_j a[b,i,j]*x[b,j,f]) > 0.5 ? 1.0f : 0.0f
//
// Block: 256 threads, handles TI=64 rows x all 64 cols of one batch.
// Thread tile: 4 rows x 4 cols (16 fp32 acc), folded into 16 fp64 masters
// per 64-chunk for decision-boundary accuracy.
// LDS: double-buffered a-tile [64][64] + x-tile [64][64] (64 KB total).

#define MAD4(ACC, S, XV)                          \
  ACC.x = fmaf((S), (XV).x, ACC.x);               \
  ACC.y = fmaf((S), (XV).y, ACC.y);               \
  ACC.z = fmaf((S), (XV).z, ACC.z);               \
  ACC.w = fmaf((S), (XV).w, ACC.w);

__global__ __launch_bounds__(256, 1)
void gnn_max_kernel(const float* __restrict__ xg,
                    const float* __restrict__ ag,
                    float* __restrict__ outg) {
  const int tid  = threadIdx.x;
  const int b    = blockIdx.y;
  const int i0   = blockIdx.x * TI;
  const int colg = tid & 15;        // 16 col-groups * 4 cols
  const int rowg = tid >> 4;        // 16 row-groups * 4 rows
  const int r0   = rowg << 2;

  __shared__ float4 sA[2][TI * JT / 4];   // [buf][row*16 + jq]
  __shared__ float4 sX[2][JT * NF / 4];   // [buf][j*16 + fq]

  const float* aRow = ag + ((size_t)b * NROW + i0) * NROW;  // + r*NROW + j
  const float* xRow = xg + (size_t)b * NROW * NF;           // + j*NF + f

  float4 acc0 = {0.f,0.f,0.f,0.f}, acc1 = {0.f,0.f,0.f,0.f};
  float4 acc2 = {0.f,0.f,0.f,0.f}, acc3 = {0.f,0.f,0.f,0.f};
  double macc[16];
#pragma unroll
  for (int i = 0; i < 16; ++i) macc[i] = 0.0;

  // ---- staging helpers (reg-staged; issue-early / write-late) ----
  auto stage_load = [&](int chunk, float4* ga, float4* gx) {
    const int j0 = chunk * JT;
#pragma unroll
    for (int s = 0; s < 4; ++s) {
      ga[s] = *(const float4*)(aRow + (size_t)(rowg + 16 * s) * NROW + j0 + colg * 4);
      gx[s] = *(const float4*)(xRow + (size_t)(j0 + rowg + 16 * s) * NF + colg * 4);
    }
  };
  auto stage_write = [&](int buf, const float4* ga, const float4* gx) {
#pragma unroll
    for (int s = 0; s < 4; ++s) {
      sA[buf][(rowg + 16 * s) * 16 + colg] = ga[s];
      sX[buf][(rowg + 16 * s) * 16 + colg] = gx[s];
    }
  };

  auto compute = [&](int buf) {
    const float4* sAv = sA[buf];
    const float4* sXv = sX[buf];
#pragma unroll
    for (int jq = 0; jq < 16; ++jq) {
      float4 a0 = sAv[(r0 + 0) * 16 + jq];
      float4 a1 = sAv[(r0 + 1) * 16 + jq];
      float4 a2 = sAv[(r0 + 2) * 16 + jq];
      float4 a3 = sAv[(r0 + 3) * 16 + jq];
      float4 x0 = sXv[(jq * 4 + 0) * 16 + colg];
      float4 x1 = sXv[(jq * 4 + 1) * 16 + colg];
      float4 x2 = sXv[(jq * 4 + 2) * 16 + colg];
      float4 x3 = sXv[(jq * 4 + 3) * 16 + colg];
      MAD4(acc0, a0.x, x0) MAD4(acc0, a0.y, x1) MAD4(acc0, a0.z, x2) MAD4(acc0, a0.w, x3)
      MAD4(acc1, a1.x, x0) MAD4(acc1, a1.y, x1) MAD4(acc1, a1.z, x2) MAD4(acc1, a1.w, x3)
      MAD4(acc2, a2.x, x0) MAD4(acc2, a2.y, x1) MAD4(acc2, a2.z, x2) MAD4(acc2, a2.w, x3)
      MAD4(acc3, a3.x, x0) MAD4(acc3, a3.y, x1) MAD4(acc3, a3.z, x2) MAD4(acc3, a3.w, x3)
    }
  };

  auto fold = [&]() {
    macc[0]  += (double)acc0.x; macc[1]  += (double)acc0.y;
    macc[2]  += (double)acc0.z; macc[3]  += (double)acc0.w;
    macc[4]  += (double)acc1.x; macc[5]  += (double)acc1.y;
    macc[6]  += (double)acc1.z; macc[7]  += (double)acc1.w;
    macc[8]  += (double)acc2.x; macc[9]  += (double)acc2.y;
    macc[10] += (double)acc2.z; macc[11] += (double)acc2.w;
    macc[12] += (double)acc3.x; macc[13] += (double)acc3.y;
    macc[14] += (double)acc3.z; macc[15] += (double)acc3.w;
    float4 z = {0.f,0.f,0.f,0.f};
    acc0 = z; acc1 = z; acc2 = z; acc3 = z;
  };

  // ---- prologue ----
  {
    float4 ga[4], gx[4];
    stage_load(0, ga, gx);
    stage_write(0, ga, gx);
  }
  __syncthreads();

  // ---- main loop: [issue loads t+1][compute t][fold][write t+1][barrier] ----
  for (int t = 0; t < NCHUNK; ++t) {
    const int cur = t & 1;
    float4 na[4], nx[4];
    if (t + 1 < NCHUNK) stage_load(t + 1, na, nx);
    compute(cur);
    fold();
    if (t + 1 < NCHUNK) stage_write(cur ^ 1, na, nx);
    __syncthreads();
  }

  // ---- epilogue: threshold + coalesced float4 stores ----
  const size_t obase = ((size_t)b * NROW + i0 + r0) * NF + colg * 4;
#pragma unroll
  for (int k = 0; k < 4; ++k) {
    float4 o;
    o.x = (macc[k * 4 + 0] > 0.5) ? 1.0f : 0.0f;
    o.y = (macc[k * 4 + 1] > 0.5) ? 1.0f : 0.0f;
    o.z = (macc[k * 4 + 2] > 0.5) ? 1.0f : 0.0f;
    o.w = (macc[k * 4 + 3] > 0.5) ? 1.0f : 0.0f;
    *(float4*)(outg + obase + (size_t)k * NF) = o;
  }
}

extern "C" void kernel_launch(void* const* d_in, const int* in_sizes, int n_in,
                              void* d_out, int out_size, void* d_ws, size_t ws_size,
                              hipStream_t stream) {
  const float* x = (const float*)d_in[0];
  const float* a = (const float*)d_in[1];
  float* out = (float*)d_out;
  dim3 grid(NROW / TI, BATCH);
  gnn_max_kernel<<<grid, dim3(256), 0, stream>>>(x, a, out);
}

// Round 2
// 75.103 us; speedup vs baseline: 3.5088x; 3.5088x over previous
//
#include <hip/hip_runtime.h>

#define BATCH 8
#define NROW  2048
#define NF    64
#define TI    64          // rows per block
#define JT    32          // j per chunk
#define JSPLIT 4
#define TOT   ((size_t)BATCH * NROW * NF)   // 1048576 outputs

// out[b,i,f] = (sum_j a[b,i,j]*x[b,j,f]) > 0.5 ? 1 : 0
//
// Main kernel: grid (32 row-tiles, 8 batches, 4 j-splits) = 1024 blocks,
// 256 threads, thread tile 4x4. Staging via global_load_lds (width 16),
// a-tile XOR-swizzled through the pre-swizzled-global-source trick.
// f32 accumulate per 32-j chunk, folded into f64 masters; f64 partials to
// d_ws; combine kernel sums 4 partials and thresholds.

#define AS1 __attribute__((address_space(1)))
#define AS3 __attribute__((address_space(3)))

__device__ __forceinline__ void gld16(const float* g, float* l) {
  __builtin_amdgcn_global_load_lds((const AS1 void*)g, (AS3 void*)l, 16, 0, 0);
}

#define MAD4(ACC, S, XV)                          \
  ACC.x = fmaf((S), (XV).x, ACC.x);               \
  ACC.y = fmaf((S), (XV).y, ACC.y);               \
  ACC.z = fmaf((S), (XV).z, ACC.z);               \
  ACC.w = fmaf((S), (XV).w, ACC.w);

template <bool DIRECT>
__global__ __launch_bounds__(256, 4)
void gemm_thresh(const float* __restrict__ xg,
                 const float* __restrict__ ag,
                 float* __restrict__ outg,
                 double* __restrict__ wsv,
                 int nch) {
  // LDS: double-buffered a[64][32] (swizzled) + x[32][64] (linear) = 32 KB
  __shared__ __align__(16) float sA[2][TI * JT];
  __shared__ __align__(16) float sX[2][JT * NF];

  const int tid  = threadIdx.x;
  const int b    = blockIdx.y;
  const int i0   = blockIdx.x * TI;
  const int colg = tid & 15;          // 16 col-groups * 4 cols
  const int rowg = tid >> 4;          // 16 row-groups * 4 rows
  const int r0   = rowg << 2;
  const int wv   = tid >> 6;          // wave id (uniform)
  const int ln   = tid & 63;
  const int key  = rowg & 3;          // a-swizzle key for this thread's 4 rows
  const int j0base = blockIdx.z * nch * JT;

  const float* aB = ag + ((size_t)b * NROW + i0) * NROW;
  const float* xB = xg + (size_t)b * NROW * NF;

  // stage chunk (j0) into buffer buf: 4 global_load_lds per thread
  auto stage = [&](int buf, int j0) {
#pragma unroll
    for (int k = 0; k < 2; ++k) {
      // a-tile: dest slot sidx (linear float4 slots); layout slot (r, qpos)
      // holds a[r][quad qpos ^ key(r)]  -> pre-swizzled global source
      const int sidx = wv * 128 + k * 64 + ln;
      const int r    = sidx >> 3;
      const int qpos = sidx & 7;
      const int kk   = (r >> 2) & 3;
      const float* gp = aB + (size_t)r * NROW + j0 + ((qpos ^ kk) << 2);
      gld16(gp, &sA[buf][(wv * 128 + k * 64) * 4]);
    }
#pragma unroll
    for (int k = 0; k < 2; ++k) {
      // x-tile: pure linear 8 KB copy
      const int sidx = wv * 128 + k * 64 + ln;
      const float* gp = xB + (size_t)j0 * NF + sidx * 4;
      gld16(gp, &sX[buf][(wv * 128 + k * 64) * 4]);
    }
  };

  float4 acc0 = {0.f,0.f,0.f,0.f}, acc1 = {0.f,0.f,0.f,0.f};
  float4 acc2 = {0.f,0.f,0.f,0.f}, acc3 = {0.f,0.f,0.f,0.f};
  double macc[16];
#pragma unroll
  for (int i = 0; i < 16; ++i) macc[i] = 0.0;

  stage(0, j0base);

  for (int t = 0; t < nch; ++t) {
    __syncthreads();   // drains chunk-t loads (vmcnt 0) + everyone done reading buf^1
    if (t + 1 < nch) stage((t + 1) & 1, j0base + (t + 1) * JT);

    const float4* Af = (const float4*)sA[t & 1];
    const float4* Xf = (const float4*)sX[t & 1];
#pragma unroll
    for (int jq = 0; jq < 8; ++jq) {
      float4 a0 = Af[(r0 + 0) * 8 + (jq ^ key)];
      float4 a1 = Af[(r0 + 1) * 8 + (jq ^ key)];
      float4 a2 = Af[(r0 + 2) * 8 + (jq ^ key)];
      float4 a3 = Af[(r0 + 3) * 8 + (jq ^ key)];
      float4 x0 = Xf[(jq * 4 + 0) * 16 + colg];
      float4 x1 = Xf[(jq * 4 + 1) * 16 + colg];
      float4 x2 = Xf[(jq * 4 + 2) * 16 + colg];
      float4 x3 = Xf[(jq * 4 + 3) * 16 + colg];
      MAD4(acc0, a0.x, x0) MAD4(acc0, a0.y, x1) MAD4(acc0, a0.z, x2) MAD4(acc0, a0.w, x3)
      MAD4(acc1, a1.x, x0) MAD4(acc1, a1.y, x1) MAD4(acc1, a1.z, x2) MAD4(acc1, a1.w, x3)
      MAD4(acc2, a2.x, x0) MAD4(acc2, a2.y, x1) MAD4(acc2, a2.z, x2) MAD4(acc2, a2.w, x3)
      MAD4(acc3, a3.x, x0) MAD4(acc3, a3.y, x1) MAD4(acc3, a3.z, x2) MAD4(acc3, a3.w, x3)
    }

    // fold f32 chunk sums into f64 masters (16 f64 adds per 512 FMAs)
    macc[0]  += (double)acc0.x; macc[1]  += (double)acc0.y;
    macc[2]  += (double)acc0.z; macc[3]  += (double)acc0.w;
    macc[4]  += (double)acc1.x; macc[5]  += (double)acc1.y;
    macc[6]  += (double)acc1.z; macc[7]  += (double)acc1.w;
    macc[8]  += (double)acc2.x; macc[9]  += (double)acc2.y;
    macc[10] += (double)acc2.z; macc[11] += (double)acc2.w;
    macc[12] += (double)acc3.x; macc[13] += (double)acc3.y;
    macc[14] += (double)acc3.z; macc[15] += (double)acc3.w;
    float4 z = {0.f,0.f,0.f,0.f};
    acc0 = z; acc1 = z; acc2 = z; acc3 = z;
  }

  if (DIRECT) {
    const size_t obase = ((size_t)b * NROW + i0 + r0) * NF + colg * 4;
#pragma unroll
    for (int k = 0; k < 4; ++k) {
      float4 o;
      o.x = (macc[k * 4 + 0] > 0.5) ? 1.0f : 0.0f;
      o.y = (macc[k * 4 + 1] > 0.5) ? 1.0f : 0.0f;
      o.z = (macc[k * 4 + 2] > 0.5) ? 1.0f : 0.0f;
      o.w = (macc[k * 4 + 3] > 0.5) ? 1.0f : 0.0f;
      *(float4*)(outg + obase + (size_t)k * NF) = o;
    }
  } else {
    double* wbase = wsv + (size_t)blockIdx.z * TOT +
                    ((size_t)b * NROW + i0 + r0) * NF + colg * 4;
#pragma unroll
    for (int k = 0; k < 4; ++k) {
      double4 o;
      o.x = macc[k * 4 + 0]; o.y = macc[k * 4 + 1];
      o.z = macc[k * 4 + 2]; o.w = macc[k * 4 + 3];
      *(double4*)(wbase + (size_t)k * NF) = o;
    }
  }
}

__global__ __launch_bounds__(256)
void combine_thresh(const double* __restrict__ wsv, float* __restrict__ outg) {
  const size_t e = (size_t)blockIdx.x * 256 + threadIdx.x;
  double s = wsv[e] + wsv[e + TOT] + wsv[e + 2 * TOT] + wsv[e + 3 * TOT];
  outg[e] = (s > 0.5) ? 1.0f : 0.0f;
}

extern "C" void kernel_launch(void* const* d_in, const int* in_sizes, int n_in,
                              void* d_out, int out_size, void* d_ws, size_t ws_size,
                              hipStream_t stream) {
  const float* x = (const float*)d_in[0];
  const float* a = (const float*)d_in[1];
  float* out = (float*)d_out;
  double* ws = (double*)d_ws;

  const size_t need = (size_t)JSPLIT * TOT * sizeof(double);   // 32 MB
  if (ws_size >= need) {
    dim3 grid(NROW / TI, BATCH, JSPLIT);
    gemm_thresh<false><<<grid, dim3(256), 0, stream>>>(x, a, out, ws,
                                                       NROW / (JSPLIT * JT));
    combine_thresh<<<dim3(TOT / 256), dim3(256), 0, stream>>>(ws, out);
  } else {
    dim3 grid(NROW / TI, BATCH, 1);
    gemm_thresh<true><<<grid, dim3(256), 0, stream>>>(x, a, out, ws, NROW / JT);
  }
}